// Round 4
// baseline (4139.943 us; speedup 1.0000x reference)
//
#include <hip/hip_runtime.h>
#include <hip/hip_bf16.h>

// ---------------- utility kernels ------------------------------------------
__global__ void zero_u32(unsigned int* __restrict__ p, long long n)
{
    long long i = (long long)blockIdx.x * 256 + threadIdx.x;
    if (i < n) p[i] = 0u;
}

__global__ void sentinel_f32(float* __restrict__ p, long long n, float v)
{
    long long i = (long long)blockIdx.x * 256 + threadIdx.x;
    if (i < n) p[i] = v;
}

// ---------------- generic GEMM: C = act(add + A @ W^T + bias) ---------------
#define BM 64
#define BN 64
#define BKK 32

template<bool RELU, bool ADD, bool BIAS>
__global__ __launch_bounds__(256) void gemm_bt(
    const float* __restrict__ A, const float* __restrict__ W,
    const float* __restrict__ addsrc, const float* __restrict__ bias,
    float* __restrict__ C, int M, int N, int K)
{
    __shared__ float As[BKK][BM + 1];
    __shared__ float Ws[BKK][BN + 1];
    const int tid = threadIdx.x;
    const int tx = tid & 15, ty = tid >> 4;
    const int row0 = blockIdx.y * BM, col0 = blockIdx.x * BN;
    float acc[4][4] = {};
    for (int k0 = 0; k0 < K; k0 += BKK) {
#pragma unroll
        for (int i = 0; i < 8; ++i) {
            int idx = tid + i * 256;         // 64 rows x 32 k
            int ml = idx >> 5, kl = idx & 31;
            int gm = row0 + ml, gk = k0 + kl;
            As[kl][ml] = (gm < M && gk < K) ? A[(size_t)gm * K + gk] : 0.f;
            int gn = col0 + ml;
            Ws[kl][ml] = (gn < N && gk < K) ? W[(size_t)gn * K + gk] : 0.f;
        }
        __syncthreads();
#pragma unroll
        for (int kk = 0; kk < BKK; ++kk) {
            float a4[4], w4[4];
#pragma unroll
            for (int i = 0; i < 4; ++i) a4[i] = As[kk][ty * 4 + i];
#pragma unroll
            for (int j = 0; j < 4; ++j) w4[j] = Ws[kk][tx * 4 + j];
#pragma unroll
            for (int i = 0; i < 4; ++i)
#pragma unroll
                for (int j = 0; j < 4; ++j)
                    acc[i][j] += a4[i] * w4[j];
        }
        __syncthreads();
    }
#pragma unroll
    for (int i = 0; i < 4; ++i) {
        int gm = row0 + ty * 4 + i;
        if (gm >= M) continue;
#pragma unroll
        for (int j = 0; j < 4; ++j) {
            int gn = col0 + tx * 4 + j;
            if (gn >= N) continue;
            float val = acc[i][j];
            if (ADD)  val += addsrc[(size_t)gm * N + gn];
            if (BIAS) val += bias[gn];
            if (RELU) val = fmaxf(val, 0.f);
            C[(size_t)gm * N + gn] = val;
        }
    }
}

// ---- MP GEMM with gathered A: C[e] = relu(inb[e] + (ma[b2a[e]]-bond[b2revb[e]]) @ wh^T)
// M = E (multiple of 64), K = N = 128 exactly: no bounds checks.
__global__ __launch_bounds__(256) void gemm_mp(
    const float* __restrict__ ma, const float* __restrict__ bond,
    const int* __restrict__ b2a, const int* __restrict__ b2revb,
    const float* __restrict__ inb, const float* __restrict__ wh,
    float* __restrict__ C)
{
    __shared__ float As[BKK][BM + 1];
    __shared__ float Ws[BKK][BN + 1];
    __shared__ int ia[BM], ir[BM];
    const int tid = threadIdx.x;
    const int tx = tid & 15, ty = tid >> 4;
    const int row0 = blockIdx.y * BM, col0 = blockIdx.x * BN;
    if (tid < 64)            ia[tid]      = b2a[row0 + tid];
    else if (tid < 128)      ir[tid - 64] = b2revb[row0 + tid - 64];
    __syncthreads();
    float acc[4][4] = {};
    for (int k0 = 0; k0 < 128; k0 += BKK) {
#pragma unroll
        for (int i = 0; i < 8; ++i) {
            int idx = tid + i * 256;
            int ml = idx >> 5, kl = idx & 31;
            int gk = k0 + kl;
            As[kl][ml] = ma[(size_t)ia[ml] * 128 + gk] - bond[(size_t)ir[ml] * 128 + gk];
            Ws[kl][ml] = wh[(size_t)(col0 + ml) * 128 + gk];
        }
        __syncthreads();
#pragma unroll
        for (int kk = 0; kk < BKK; ++kk) {
            float a4[4], w4[4];
#pragma unroll
            for (int i = 0; i < 4; ++i) a4[i] = As[kk][ty * 4 + i];
#pragma unroll
            for (int j = 0; j < 4; ++j) w4[j] = Ws[kk][tx * 4 + j];
#pragma unroll
            for (int i = 0; i < 4; ++i)
#pragma unroll
                for (int j = 0; j < 4; ++j)
                    acc[i][j] += a4[i] * w4[j];
        }
        __syncthreads();
    }
#pragma unroll
    for (int i = 0; i < 4; ++i) {
        int gm = row0 + ty * 4 + i;
#pragma unroll
        for (int j = 0; j < 4; ++j) {
            int gn = col0 + tx * 4 + j;
            float val = inb[(size_t)gm * 128 + gn] + acc[i][j];
            C[(size_t)gm * 128 + gn] = fmaxf(val, 0.f);
        }
    }
}

// ---------------- aggregation: ma[n] += sum_j(bond[a2b]) * max_j(bond[a2b]) -
__global__ __launch_bounds__(256) void agg_kernel(
    const float* __restrict__ bond, const int* __restrict__ a2b,
    float* __restrict__ ma, int N)
{
    int n = blockIdx.x * 2 + (threadIdx.x >> 7);
    int d = threadIdx.x & 127;
    if (n >= N) return;
    const int* ix = a2b + (size_t)n * 6;
    float s = 0.f, mx = -3.0e38f;
#pragma unroll
    for (int j = 0; j < 6; ++j) {
        float val = bond[(size_t)ix[j] * 128 + d];
        s += val; mx = fmaxf(mx, val);
    }
    ma[(size_t)n * 128 + d] += s * mx;
}

// ---------------- CSR build over dst ----------------------------------------
__global__ void count_kernel(const int* __restrict__ dst, int* __restrict__ counts, int E)
{
    int e = blockIdx.x * 256 + threadIdx.x;
    if (e < E) atomicAdd(&counts[dst[e]], 1);
}

__global__ __launch_bounds__(1024) void scan_kernel(
    const int* __restrict__ counts, int* __restrict__ offsets, int N)
{
    __shared__ int sums[1024];
    int t = threadIdx.x;
    int chunk = (N + 1023) >> 10;
    int b = t * chunk;
    int e = b + chunk; if (e > N) e = N;
    int s = 0;
    for (int i = b; i < e; ++i) s += counts[i];
    sums[t] = s;
    __syncthreads();
    for (int off = 1; off < 1024; off <<= 1) {
        int v = (t >= off) ? sums[t - off] : 0;
        __syncthreads();
        sums[t] += v;
        __syncthreads();
    }
    int run = sums[t] - s;   // exclusive prefix
    for (int i = b; i < e; ++i) { offsets[i] = run; run += counts[i]; }
    if (t == 1023) offsets[N] = sums[1023];
}

__global__ void fill_kernel(const int* __restrict__ dst, const int* __restrict__ offsets,
                            int* __restrict__ cursor, int* __restrict__ elist, int E)
{
    int e = blockIdx.x * 256 + threadIdx.x;
    if (e < E) {
        int d = dst[e];
        int pos = offsets[d] + atomicAdd(&cursor[d], 1);
        elist[pos] = e;
    }
}

// ---------------- attention pass 1: logits -> normalized alpha --------------
__global__ __launch_bounds__(256) void attn_pass1(
    const float* __restrict__ qh, const float* __restrict__ kh,
    const float* __restrict__ eh, const int* __restrict__ srcA,
    const int* __restrict__ offs, const int* __restrict__ elist,
    float* __restrict__ alpha, int N)
{
    int n = blockIdx.x * 4 + (threadIdx.x >> 6);
    if (n >= N) return;
    int l = threadIdx.x & 63;
    float2 q2 = ((const float2*)(qh + (size_t)n * 128))[l];
    int b = offs[n], en = offs[n + 1];
    float m = -3.0e38f, denom = 0.f;
    for (int ie = b; ie < en; ++ie) {
        int e = elist[ie];
        int s = srcA[e];
        float2 k2 = ((const float2*)(kh + (size_t)s * 128))[l];
        float2 e2 = ((const float2*)(eh + (size_t)e * 128))[l];
        float part = q2.x * (k2.x + e2.x) + q2.y * (k2.y + e2.y);
        part += __shfl_xor(part, 1);  part += __shfl_xor(part, 2);
        part += __shfl_xor(part, 4);  part += __shfl_xor(part, 8);
        part += __shfl_xor(part, 16); part += __shfl_xor(part, 32);
        float logit = part * 0.08838834764831845f;   // 1/sqrt(128)
        if (l == 0) alpha[ie] = logit;
        float mn = fmaxf(m, logit);
        denom = denom * __expf(m - mn) + __expf(logit - mn);
        m = mn;
    }
    if (l == 0 && b < en) {
        float invd = 1.f / (denom + 1e-16f);
        for (int ie = b; ie < en; ++ie)
            alpha[ie] = __expf(alpha[ie] - m) * invd;
    }
}

// ---------------- attention pass 2: outsum += mean_h alpha*(v[src]+eattr) ---
__global__ __launch_bounds__(256) void attn_pass2(
    const float* __restrict__ vh, const float* __restrict__ eh,
    const int* __restrict__ srcA, const int* __restrict__ offs,
    const int* __restrict__ elist, const float* __restrict__ alpha,
    float* __restrict__ outsum, int N)
{
    int n = blockIdx.x * 4 + (threadIdx.x >> 6);
    if (n >= N) return;
    int l = threadIdx.x & 63;
    int b = offs[n], en = offs[n + 1];
    float a0 = 0.f, a1 = 0.f;
    for (int ie = b; ie < en; ++ie) {
        int e = elist[ie];
        int s = srcA[e];
        float a = alpha[ie];
        float2 v2 = ((const float2*)(vh + (size_t)s * 128))[l];
        float2 e2 = ((const float2*)(eh + (size_t)e * 128))[l];
        a0 += a * (v2.x + e2.x);
        a1 += a * (v2.y + e2.y);
    }
    float* op = outsum + (size_t)n * 128 + 2 * l;
    op[0] += 0.125f * a0;
    op[1] += 0.125f * a1;
}

// ---------------- Set2Set ----------------------------------------------------
__global__ void qv_kernel(const float* __restrict__ bih, const float* __restrict__ bhh,
                          float* __restrict__ qv)
{
    int t = threadIdx.x;  // 128 threads
    float gi = bih[t] + bhh[t];
    float gg = bih[256 + t] + bhh[256 + t];
    float go = bih[384 + t] + bhh[384 + t];
    float sig_i = 1.f / (1.f + __expf(-gi));
    float c = sig_i * tanhf(gg);
    float sig_o = 1.f / (1.f + __expf(-go));
    qv[t] = sig_o * tanhf(c);
}

__global__ __launch_bounds__(256) void s2s_kernel(
    const float* __restrict__ ah, const float* __restrict__ qv,
    const float* __restrict__ wo_w, const float* __restrict__ wo_b,
    float* __restrict__ out, int M)
{
    __shared__ float rsh[4][128];
    __shared__ float qsh[128];
    int wv = threadIdx.x >> 6, l = threadIdx.x & 63;
    if (threadIdx.x < 128) qsh[threadIdx.x] = qv[threadIdx.x];
    __syncthreads();
    int m = blockIdx.x * 4 + wv;
    bool active = (m < M);
    if (active) {
        const float* x = ah + (size_t)m * 20 * 128;
        float q0 = qsh[2 * l], q1 = qsh[2 * l + 1];
        float e[20]; float mx = -3.0e38f;
#pragma unroll
        for (int a = 0; a < 20; ++a) {
            float part = x[a * 128 + 2 * l] * q0 + x[a * 128 + 2 * l + 1] * q1;
            part += __shfl_xor(part, 1);  part += __shfl_xor(part, 2);
            part += __shfl_xor(part, 4);  part += __shfl_xor(part, 8);
            part += __shfl_xor(part, 16); part += __shfl_xor(part, 32);
            e[a] = part; mx = fmaxf(mx, part);
        }
        float sum = 0.f;
#pragma unroll
        for (int a = 0; a < 20; ++a) { e[a] = __expf(e[a] - mx); sum += e[a]; }
        float invs = 1.f / (sum + 1e-16f);
        float r0 = 0.f, r1 = 0.f;
#pragma unroll
        for (int a = 0; a < 20; ++a) {
            float w = e[a] * invs;
            r0 += w * x[a * 128 + 2 * l];
            r1 += w * x[a * 128 + 2 * l + 1];
        }
        rsh[wv][2 * l] = r0; rsh[wv][2 * l + 1] = r1;
    }
    __syncthreads();
    if (active) {
#pragma unroll
        for (int dd = 0; dd < 2; ++dd) {
            int d = 2 * l + dd;
            float acc = wo_b[d];
            const float* wr = wo_w + (size_t)d * 256;
            for (int j = 0; j < 128; ++j)
                acc += wr[j] * qsh[j] + wr[128 + j] * rsh[wv][j];
            out[(size_t)m * 128 + d] = acc;
        }
    }
}

// ---------------- launch -----------------------------------------------------
extern "C" void kernel_launch(void* const* d_in, const int* in_sizes, int n_in,
                              void* d_out, int out_size, void* d_ws, size_t ws_size,
                              hipStream_t stream)
{
    const int N = 60000, E = 120000, FA = 133, FB = 147;
    const float* f_atoms  = (const float*)d_in[0];
    const float* f_bonds  = (const float*)d_in[1];
    const float* wi_atom  = (const float*)d_in[2];
    const float* wi_bond  = (const float*)d_in[3];
    const float* wh[3]    = { (const float*)d_in[4], (const float*)d_in[5], (const float*)d_in[6] };
    const float* q_w      = (const float*)d_in[7];
    const float* q_b      = (const float*)d_in[8];
    const float* k_w      = (const float*)d_in[9];
    const float* k_b      = (const float*)d_in[10];
    const float* v_w      = (const float*)d_in[11];
    const float* v_b      = (const float*)d_in[12];
    const float* e_w      = (const float*)d_in[13];
    const float* skip_w   = (const float*)d_in[14];
    const float* skip_b   = (const float*)d_in[15];
    const float* lstm_bih = (const float*)d_in[18];
    const float* lstm_bhh = (const float*)d_in[19];
    const float* wo_w     = (const float*)d_in[20];
    const float* wo_b     = (const float*)d_in[21];
    const int* a2b    = (const int*)d_in[22];
    const int* b2a    = (const int*)d_in[23];
    const int* b2revb = (const int*)d_in[24];
    const int* bonds  = (const int*)d_in[25];
    const int* srcA = bonds;
    const int* dstA = bonds + E;

    // ---- workspace plan (~247.5 MB) ----
    const size_t NB = (size_t)N * 128;   // 7.68M floats (30.72 MB)
    const size_t EB = (size_t)E * 128;   // 15.36M floats (61.44 MB)
    char* ws = (char*)d_ws;
    size_t off = 0;
    auto alloc = [&](size_t bytes) -> char* {
        char* p = ws + off; off += (bytes + 255) & ~255ULL; return p;
    };
    float* msg_atom = (float*)alloc(NB * 4);            // atoms, whole run
    float* B1       = (float*)alloc(EB * 4);            // input_bond -> q|k -> v|k
    float* B2       = (float*)alloc(EB * 4);            // bond ping (final msg_bond)
    float* B3       = (float*)alloc(EB * 4);            // bond pong -> eattr_h
    float* outsum   = (float*)alloc(NB * 4);            // skip-init, attn accum, = ah
    float* alpha    = (float*)alloc((size_t)E * 4);
    int* counts  = (int*)alloc((size_t)N * 4);
    int* offsets = (int*)alloc((size_t)(N + 1) * 4);
    int* cursor  = (int*)alloc((size_t)N * 4);
    int* elist   = (int*)alloc((size_t)E * 4);
    float* qvb   = (float*)alloc(128 * 4);

    if (off > ws_size) {
        // diagnostic sentinel: error ~1e9 => workspace too small
        long long n = out_size;
        sentinel_f32<<<(int)((n + 255) / 256), 256, 0, stream>>>((float*)d_out, n, 1.0e9f);
        return;
    }

    float* q_h = B1;            // [N,128]
    float* k_h = B1 + NB;       // [N,128]
    float* v_h = B1;            // [N,128] overwrites q after pass1
    float* e_h = B3;            // [E,128]

    const int gyN = (N + BM - 1) / BM;   // 938
    const int gyE = E / BM;              // 1875 exact

    // 0. zero CSR state (graph-capture-safe, replay-safe)
    zero_u32<<<(N + 255) / 256, 256, 0, stream>>>((unsigned int*)counts, N);
    zero_u32<<<(N + 255) / 256, 256, 0, stream>>>((unsigned int*)cursor, N);

    // 1. input projections
    gemm_bt<true, false, false><<<dim3(2, gyN), 256, 0, stream>>>(
        f_atoms, wi_atom, nullptr, nullptr, msg_atom, N, 128, FA);
    gemm_bt<true, false, false><<<dim3(2, gyE), 256, 0, stream>>>(
        f_bonds, wi_bond, nullptr, nullptr, B1, E, 128, FB);

    // 2. CSR over dst
    count_kernel<<<(E + 255) / 256, 256, 0, stream>>>(dstA, counts, E);
    scan_kernel<<<1, 1024, 0, stream>>>(counts, offsets, N);
    fill_kernel<<<(E + 255) / 256, 256, 0, stream>>>(dstA, offsets, cursor, elist, E);

    // 3. message passing: B1(input) -> B2 -> B3 -> B2 (gather-fused GEMM)
    const float* cur = B1;
    float* nxt[3] = { B2, B3, B2 };
    for (int it = 0; it < 3; ++it) {
        agg_kernel<<<N / 2, 256, 0, stream>>>(cur, a2b, msg_atom, N);
        gemm_mp<<<dim3(2, gyE), 256, 0, stream>>>(
            msg_atom, cur, b2a, b2revb, B1, wh[it], nxt[it]);
        cur = nxt[it];
    }
    // final message_bond = B2; B1, B3 now dead

    // 4. outsum = msg_atom @ skip_w.T + skip_b   (attention adds on top)
    gemm_bt<false, false, true><<<dim3(2, gyN), 256, 0, stream>>>(
        msg_atom, skip_w, nullptr, skip_b, outsum, N, 128, 128);

    // 5. TransformerConv, one head at a time
    for (int h = 0; h < 8; ++h) {
        const size_t w_off = (size_t)h * 128 * 128;
        gemm_bt<false, false, true><<<dim3(2, gyN), 256, 0, stream>>>(
            msg_atom, q_w + w_off, nullptr, q_b + h * 128, q_h, N, 128, 128);
        gemm_bt<false, false, true><<<dim3(2, gyN), 256, 0, stream>>>(
            msg_atom, k_w + w_off, nullptr, k_b + h * 128, k_h, N, 128, 128);
        gemm_bt<false, false, false><<<dim3(2, gyE), 256, 0, stream>>>(
            B2, e_w + w_off, nullptr, nullptr, e_h, E, 128, 128);
        attn_pass1<<<(N + 3) / 4, 256, 0, stream>>>(
            q_h, k_h, e_h, srcA, offsets, elist, alpha, N);
        gemm_bt<false, false, true><<<dim3(2, gyN), 256, 0, stream>>>(
            msg_atom, v_w + w_off, nullptr, v_b + h * 128, v_h, N, 128, 128);
        attn_pass2<<<(N + 3) / 4, 256, 0, stream>>>(
            v_h, e_h, srcA, offsets, elist, alpha, outsum, N);
    }

    // 6. Set2Set + output projection (outsum == atom_hiddens)
    qv_kernel<<<1, 128, 0, stream>>>(lstm_bih, lstm_bhh, qvb);
    const int M = N / 20;  // 3000 molecules
    s2s_kernel<<<(M + 3) / 4, 256, 0, stream>>>(outsum, qvb, wo_w, wo_b, (float*)d_out, M);
}

// Round 5
// 2535.185 us; speedup vs baseline: 1.6330x; 1.6330x over previous
//
#include <hip/hip_runtime.h>
#include <hip/hip_bf16.h>

// ---------------- utility kernels ------------------------------------------
__global__ void zero_u32(unsigned int* __restrict__ p, long long n)
{
    long long i = (long long)blockIdx.x * 256 + threadIdx.x;
    if (i < n) p[i] = 0u;
}

__global__ void sentinel_f32(float* __restrict__ p, long long n, float v)
{
    long long i = (long long)blockIdx.x * 256 + threadIdx.x;
    if (i < n) p[i] = v;
}

// ---------------- high-intensity GEMM: C[M,128] = act(add + A[M,K]@W[128,K]^T + bias)
// 128x128 block tile, 8x8 per thread, K-transposed LDS with b128 fragment reads.
template<bool RELU, bool ADD, bool BIAS>
__global__ __launch_bounds__(256) void gemm128(
    const float* __restrict__ A, const float* __restrict__ W,
    const float* __restrict__ addsrc, const float* __restrict__ bias,
    float* __restrict__ C, int M, int K)
{
    __shared__ float As[32][132];   // [k][m], pad 4 floats
    __shared__ float Ws[32][132];   // [k][n]
    const int tid = threadIdx.x;
    const int tx = tid & 15, ty = tid >> 4;
    const int row0 = blockIdx.x * 128;
    const int srow = tid >> 3;           // 0..31
    const int sk4  = (tid & 7) * 4;      // 0..28
    float acc[8][8] = {};
    for (int k0 = 0; k0 < K; k0 += 32) {
        const bool fullk = (k0 + 32 <= K);
#pragma unroll
        for (int c = 0; c < 4; ++c) {
            int r = srow + c * 32;       // 0..127
            int gm = row0 + r;
            float4 av = make_float4(0.f, 0.f, 0.f, 0.f);
            if (gm < M) {
                const float* src = A + (size_t)gm * K + k0 + sk4;
                if (fullk) av = *(const float4*)src;
                else {
                    if (k0 + sk4     < K) av.x = src[0];
                    if (k0 + sk4 + 1 < K) av.y = src[1];
                    if (k0 + sk4 + 2 < K) av.z = src[2];
                    if (k0 + sk4 + 3 < K) av.w = src[3];
                }
            }
            As[sk4 + 0][r] = av.x; As[sk4 + 1][r] = av.y;
            As[sk4 + 2][r] = av.z; As[sk4 + 3][r] = av.w;
            const float* wsrc = W + (size_t)r * K + k0 + sk4;   // W row r always valid
            float4 wv = make_float4(0.f, 0.f, 0.f, 0.f);
            if (fullk) wv = *(const float4*)wsrc;
            else {
                if (k0 + sk4     < K) wv.x = wsrc[0];
                if (k0 + sk4 + 1 < K) wv.y = wsrc[1];
                if (k0 + sk4 + 2 < K) wv.z = wsrc[2];
                if (k0 + sk4 + 3 < K) wv.w = wsrc[3];
            }
            Ws[sk4 + 0][r] = wv.x; Ws[sk4 + 1][r] = wv.y;
            Ws[sk4 + 2][r] = wv.z; Ws[sk4 + 3][r] = wv.w;
        }
        __syncthreads();
#pragma unroll
        for (int kk = 0; kk < 32; ++kk) {
            float a[8], w[8];
            *(float4*)&a[0] = *(const float4*)&As[kk][ty * 4];
            *(float4*)&a[4] = *(const float4*)&As[kk][64 + ty * 4];
            *(float4*)&w[0] = *(const float4*)&Ws[kk][tx * 4];
            *(float4*)&w[4] = *(const float4*)&Ws[kk][64 + tx * 4];
#pragma unroll
            for (int i = 0; i < 8; ++i)
#pragma unroll
                for (int j = 0; j < 8; ++j)
                    acc[i][j] += a[i] * w[j];
        }
        __syncthreads();
    }
    float bs[8];
    if (BIAS) {
#pragma unroll
        for (int j = 0; j < 4; ++j) {
            bs[j]     = bias[tx * 4 + j];
            bs[j + 4] = bias[64 + tx * 4 + j];
        }
    }
#pragma unroll
    for (int i = 0; i < 8; ++i) {
        int r = (i < 4) ? (ty * 4 + i) : (64 + ty * 4 + i - 4);
        int gm = row0 + r;
        if (gm >= M) continue;
#pragma unroll
        for (int jh = 0; jh < 2; ++jh) {
            int cc = jh * 64 + tx * 4;
            float4 v;
            v.x = acc[i][jh * 4 + 0]; v.y = acc[i][jh * 4 + 1];
            v.z = acc[i][jh * 4 + 2]; v.w = acc[i][jh * 4 + 3];
            if (ADD) {
                float4 o = *(const float4*)&addsrc[(size_t)gm * 128 + cc];
                v.x += o.x; v.y += o.y; v.z += o.z; v.w += o.w;
            }
            if (BIAS) {
                v.x += bs[jh * 4 + 0]; v.y += bs[jh * 4 + 1];
                v.z += bs[jh * 4 + 2]; v.w += bs[jh * 4 + 3];
            }
            if (RELU) {
                v.x = fmaxf(v.x, 0.f); v.y = fmaxf(v.y, 0.f);
                v.z = fmaxf(v.z, 0.f); v.w = fmaxf(v.w, 0.f);
            }
            *(float4*)&C[(size_t)gm * 128 + cc] = v;
        }
    }
}

// ---- MP GEMM, gathered A: C[e] = relu(inb[e] + (ma[b2a[e]]-bond[b2revb[e]]) @ wh^T)
// K = 128 exactly.
__global__ __launch_bounds__(256) void gemm_mp(
    const float* __restrict__ ma, const float* __restrict__ bond,
    const int* __restrict__ b2a, const int* __restrict__ b2revb,
    const float* __restrict__ inb, const float* __restrict__ wh,
    float* __restrict__ C, int E)
{
    __shared__ float As[32][132];
    __shared__ float Ws[32][132];
    __shared__ int ia[128], ir[128];
    const int tid = threadIdx.x;
    const int tx = tid & 15, ty = tid >> 4;
    const int row0 = blockIdx.x * 128;
    const int srow = tid >> 3;
    const int sk4  = (tid & 7) * 4;
    if (tid < 128) {
        int g = row0 + tid;
        ia[tid] = (g < E) ? b2a[g] : 0;
        ir[tid] = (g < E) ? b2revb[g] : 0;
    }
    __syncthreads();
    float acc[8][8] = {};
    for (int k0 = 0; k0 < 128; k0 += 32) {
#pragma unroll
        for (int c = 0; c < 4; ++c) {
            int r = srow + c * 32;
            const float* pa = ma   + (size_t)ia[r] * 128 + k0 + sk4;
            const float* pb = bond + (size_t)ir[r] * 128 + k0 + sk4;
            float4 x = *(const float4*)pa;
            float4 y = *(const float4*)pb;
            As[sk4 + 0][r] = x.x - y.x; As[sk4 + 1][r] = x.y - y.y;
            As[sk4 + 2][r] = x.z - y.z; As[sk4 + 3][r] = x.w - y.w;
            float4 wv = *(const float4*)(wh + (size_t)r * 128 + k0 + sk4);
            Ws[sk4 + 0][r] = wv.x; Ws[sk4 + 1][r] = wv.y;
            Ws[sk4 + 2][r] = wv.z; Ws[sk4 + 3][r] = wv.w;
        }
        __syncthreads();
#pragma unroll
        for (int kk = 0; kk < 32; ++kk) {
            float a[8], w[8];
            *(float4*)&a[0] = *(const float4*)&As[kk][ty * 4];
            *(float4*)&a[4] = *(const float4*)&As[kk][64 + ty * 4];
            *(float4*)&w[0] = *(const float4*)&Ws[kk][tx * 4];
            *(float4*)&w[4] = *(const float4*)&Ws[kk][64 + tx * 4];
#pragma unroll
            for (int i = 0; i < 8; ++i)
#pragma unroll
                for (int j = 0; j < 8; ++j)
                    acc[i][j] += a[i] * w[j];
        }
        __syncthreads();
    }
#pragma unroll
    for (int i = 0; i < 8; ++i) {
        int r = (i < 4) ? (ty * 4 + i) : (64 + ty * 4 + i - 4);
        int gm = row0 + r;
        if (gm >= E) continue;
#pragma unroll
        for (int jh = 0; jh < 2; ++jh) {
            int cc = jh * 64 + tx * 4;
            float4 o = *(const float4*)&inb[(size_t)gm * 128 + cc];
            float4 v;
            v.x = fmaxf(acc[i][jh * 4 + 0] + o.x, 0.f);
            v.y = fmaxf(acc[i][jh * 4 + 1] + o.y, 0.f);
            v.z = fmaxf(acc[i][jh * 4 + 2] + o.z, 0.f);
            v.w = fmaxf(acc[i][jh * 4 + 3] + o.w, 0.f);
            *(float4*)&C[(size_t)gm * 128 + cc] = v;
        }
    }
}

// ---------------- aggregation: ma[n] += sum_j(bond[a2b]) * max_j(bond[a2b]) -
__global__ __launch_bounds__(256) void agg_kernel(
    const float* __restrict__ bond, const int* __restrict__ a2b,
    float* __restrict__ ma, int N)
{
    int n = blockIdx.x * 2 + (threadIdx.x >> 7);
    int d = threadIdx.x & 127;
    if (n >= N) return;
    const int* ix = a2b + (size_t)n * 6;
    float s = 0.f, mx = -3.0e38f;
#pragma unroll
    for (int j = 0; j < 6; ++j) {
        float val = bond[(size_t)ix[j] * 128 + d];
        s += val; mx = fmaxf(mx, val);
    }
    ma[(size_t)n * 128 + d] += s * mx;
}

// ---------------- CSR build over dst ----------------------------------------
__global__ void count_kernel(const int* __restrict__ dst, int* __restrict__ counts, int E)
{
    int e = blockIdx.x * 256 + threadIdx.x;
    if (e < E) atomicAdd(&counts[dst[e]], 1);
}

__global__ __launch_bounds__(1024) void scan_kernel(
    const int* __restrict__ counts, int* __restrict__ offsets, int N)
{
    __shared__ int sums[1024];
    int t = threadIdx.x;
    int chunk = (N + 1023) >> 10;
    int b = t * chunk;
    int e = b + chunk; if (e > N) e = N;
    int s = 0;
    for (int i = b; i < e; ++i) s += counts[i];
    sums[t] = s;
    __syncthreads();
    for (int off = 1; off < 1024; off <<= 1) {
        int v = (t >= off) ? sums[t - off] : 0;
        __syncthreads();
        sums[t] += v;
        __syncthreads();
    }
    int run = sums[t] - s;   // exclusive prefix
    for (int i = b; i < e; ++i) { offsets[i] = run; run += counts[i]; }
    if (t == 1023) offsets[N] = sums[1023];
}

__global__ void fill_kernel(const int* __restrict__ dst, const int* __restrict__ offsets,
                            int* __restrict__ cursor, int* __restrict__ elist, int E)
{
    int e = blockIdx.x * 256 + threadIdx.x;
    if (e < E) {
        int d = dst[e];
        int pos = offsets[d] + atomicAdd(&cursor[d], 1);
        elist[pos] = e;
    }
}

// ---------------- attention pass 1: logits -> normalized alpha --------------
__global__ __launch_bounds__(256) void attn_pass1(
    const float* __restrict__ qh, const float* __restrict__ kh,
    const float* __restrict__ eh, const int* __restrict__ srcA,
    const int* __restrict__ offs, const int* __restrict__ elist,
    float* __restrict__ alpha, int N)
{
    int n = blockIdx.x * 4 + (threadIdx.x >> 6);
    if (n >= N) return;
    int l = threadIdx.x & 63;
    float2 q2 = ((const float2*)(qh + (size_t)n * 128))[l];
    int b = offs[n], en = offs[n + 1];
    float m = -3.0e38f, denom = 0.f;
    for (int ie = b; ie < en; ++ie) {
        int e = elist[ie];
        int s = srcA[e];
        float2 k2 = ((const float2*)(kh + (size_t)s * 128))[l];
        float2 e2 = ((const float2*)(eh + (size_t)e * 128))[l];
        float part = q2.x * (k2.x + e2.x) + q2.y * (k2.y + e2.y);
        part += __shfl_xor(part, 1);  part += __shfl_xor(part, 2);
        part += __shfl_xor(part, 4);  part += __shfl_xor(part, 8);
        part += __shfl_xor(part, 16); part += __shfl_xor(part, 32);
        float logit = part * 0.08838834764831845f;   // 1/sqrt(128)
        if (l == 0) alpha[ie] = logit;
        float mn = fmaxf(m, logit);
        denom = denom * __expf(m - mn) + __expf(logit - mn);
        m = mn;
    }
    if (l == 0 && b < en) {
        float invd = 1.f / (denom + 1e-16f);
        for (int ie = b; ie < en; ++ie)
            alpha[ie] = __expf(alpha[ie] - m) * invd;
    }
}

// ---------------- attention pass 2: outsum += mean_h alpha*(v[src]+eattr) ---
__global__ __launch_bounds__(256) void attn_pass2(
    const float* __restrict__ vh, const float* __restrict__ eh,
    const int* __restrict__ srcA, const int* __restrict__ offs,
    const int* __restrict__ elist, const float* __restrict__ alpha,
    float* __restrict__ outsum, int N)
{
    int n = blockIdx.x * 4 + (threadIdx.x >> 6);
    if (n >= N) return;
    int l = threadIdx.x & 63;
    int b = offs[n], en = offs[n + 1];
    float a0 = 0.f, a1 = 0.f;
    for (int ie = b; ie < en; ++ie) {
        int e = elist[ie];
        int s = srcA[e];
        float a = alpha[ie];
        float2 v2 = ((const float2*)(vh + (size_t)s * 128))[l];
        float2 e2 = ((const float2*)(eh + (size_t)e * 128))[l];
        a0 += a * (v2.x + e2.x);
        a1 += a * (v2.y + e2.y);
    }
    float* op = outsum + (size_t)n * 128 + 2 * l;
    op[0] += 0.125f * a0;
    op[1] += 0.125f * a1;
}

// ---------------- Set2Set ----------------------------------------------------
__global__ void qv_kernel(const float* __restrict__ bih, const float* __restrict__ bhh,
                          float* __restrict__ qv)
{
    int t = threadIdx.x;  // 128 threads
    float gi = bih[t] + bhh[t];
    float gg = bih[256 + t] + bhh[256 + t];
    float go = bih[384 + t] + bhh[384 + t];
    float sig_i = 1.f / (1.f + __expf(-gi));
    float c = sig_i * tanhf(gg);
    float sig_o = 1.f / (1.f + __expf(-go));
    qv[t] = sig_o * tanhf(c);
}

__global__ __launch_bounds__(256) void s2s_kernel(
    const float* __restrict__ ah, const float* __restrict__ qv,
    const float* __restrict__ wo_w, const float* __restrict__ wo_b,
    float* __restrict__ out, int M)
{
    __shared__ float rsh[4][128];
    __shared__ float qsh[128];
    int wv = threadIdx.x >> 6, l = threadIdx.x & 63;
    if (threadIdx.x < 128) qsh[threadIdx.x] = qv[threadIdx.x];
    __syncthreads();
    int m = blockIdx.x * 4 + wv;
    bool active = (m < M);
    if (active) {
        const float* x = ah + (size_t)m * 20 * 128;
        float q0 = qsh[2 * l], q1 = qsh[2 * l + 1];
        float e[20]; float mx = -3.0e38f;
#pragma unroll
        for (int a = 0; a < 20; ++a) {
            float part = x[a * 128 + 2 * l] * q0 + x[a * 128 + 2 * l + 1] * q1;
            part += __shfl_xor(part, 1);  part += __shfl_xor(part, 2);
            part += __shfl_xor(part, 4);  part += __shfl_xor(part, 8);
            part += __shfl_xor(part, 16); part += __shfl_xor(part, 32);
            e[a] = part; mx = fmaxf(mx, part);
        }
        float sum = 0.f;
#pragma unroll
        for (int a = 0; a < 20; ++a) { e[a] = __expf(e[a] - mx); sum += e[a]; }
        float invs = 1.f / (sum + 1e-16f);
        float r0 = 0.f, r1 = 0.f;
#pragma unroll
        for (int a = 0; a < 20; ++a) {
            float w = e[a] * invs;
            r0 += w * x[a * 128 + 2 * l];
            r1 += w * x[a * 128 + 2 * l + 1];
        }
        rsh[wv][2 * l] = r0; rsh[wv][2 * l + 1] = r1;
    }
    __syncthreads();
    if (active) {
#pragma unroll
        for (int dd = 0; dd < 2; ++dd) {
            int d = 2 * l + dd;
            float acc = wo_b[d];
            const float* wr = wo_w + (size_t)d * 256;
            for (int j = 0; j < 128; ++j)
                acc += wr[j] * qsh[j] + wr[128 + j] * rsh[wv][j];
            out[(size_t)m * 128 + d] = acc;
        }
    }
}

// ---------------- launch -----------------------------------------------------
extern "C" void kernel_launch(void* const* d_in, const int* in_sizes, int n_in,
                              void* d_out, int out_size, void* d_ws, size_t ws_size,
                              hipStream_t stream)
{
    const int N = 60000, E = 120000, FA = 133, FB = 147;
    const float* f_atoms  = (const float*)d_in[0];
    const float* f_bonds  = (const float*)d_in[1];
    const float* wi_atom  = (const float*)d_in[2];
    const float* wi_bond  = (const float*)d_in[3];
    const float* wh[3]    = { (const float*)d_in[4], (const float*)d_in[5], (const float*)d_in[6] };
    const float* q_w      = (const float*)d_in[7];
    const float* q_b      = (const float*)d_in[8];
    const float* k_w      = (const float*)d_in[9];
    const float* k_b      = (const float*)d_in[10];
    const float* v_w      = (const float*)d_in[11];
    const float* v_b      = (const float*)d_in[12];
    const float* e_w      = (const float*)d_in[13];
    const float* skip_w   = (const float*)d_in[14];
    const float* skip_b   = (const float*)d_in[15];
    const float* lstm_bih = (const float*)d_in[18];
    const float* lstm_bhh = (const float*)d_in[19];
    const float* wo_w     = (const float*)d_in[20];
    const float* wo_b     = (const float*)d_in[21];
    const int* a2b    = (const int*)d_in[22];
    const int* b2a    = (const int*)d_in[23];
    const int* b2revb = (const int*)d_in[24];
    const int* bonds  = (const int*)d_in[25];
    const int* srcA = bonds;
    const int* dstA = bonds + E;

    // ---- workspace plan (~247.5 MB, proven to fit) ----
    const size_t NB = (size_t)N * 128;
    const size_t EB = (size_t)E * 128;
    char* ws = (char*)d_ws;
    size_t off = 0;
    auto alloc = [&](size_t bytes) -> char* {
        char* p = ws + off; off += (bytes + 255) & ~255ULL; return p;
    };
    float* msg_atom = (float*)alloc(NB * 4);            // atoms, whole run
    float* B1       = (float*)alloc(EB * 4);            // input_bond -> q|k -> v|k
    float* B2       = (float*)alloc(EB * 4);            // bond ping (final msg_bond)
    float* B3       = (float*)alloc(EB * 4);            // bond pong -> eattr_h
    float* outsum   = (float*)alloc(NB * 4);            // skip-init, attn accum, = ah
    float* alpha    = (float*)alloc((size_t)E * 4);
    int* counts  = (int*)alloc((size_t)N * 4);
    int* offsets = (int*)alloc((size_t)(N + 1) * 4);
    int* cursor  = (int*)alloc((size_t)N * 4);
    int* elist   = (int*)alloc((size_t)E * 4);
    float* qvb   = (float*)alloc(128 * 4);

    if (off > ws_size) {
        long long n = out_size;
        sentinel_f32<<<(int)((n + 255) / 256), 256, 0, stream>>>((float*)d_out, n, 1.0e9f);
        return;
    }

    float* q_h = B1;            // [N,128]
    float* k_h = B1 + NB;       // [N,128]
    float* v_h = B1;            // [N,128] overwrites q after pass1
    float* e_h = B3;            // [E,128]

    const int gN = (N + 127) / 128;   // 469
    const int gE = (E + 127) / 128;   // 938

    // 0. zero CSR state (graph-capture-safe, replay-safe)
    zero_u32<<<(N + 255) / 256, 256, 0, stream>>>((unsigned int*)counts, N);
    zero_u32<<<(N + 255) / 256, 256, 0, stream>>>((unsigned int*)cursor, N);

    // 1. input projections
    gemm128<true, false, false><<<gN, 256, 0, stream>>>(
        f_atoms, wi_atom, nullptr, nullptr, msg_atom, N, FA);
    gemm128<true, false, false><<<gE, 256, 0, stream>>>(
        f_bonds, wi_bond, nullptr, nullptr, B1, E, FB);

    // 2. CSR over dst
    count_kernel<<<(E + 255) / 256, 256, 0, stream>>>(dstA, counts, E);
    scan_kernel<<<1, 1024, 0, stream>>>(counts, offsets, N);
    fill_kernel<<<(E + 255) / 256, 256, 0, stream>>>(dstA, offsets, cursor, elist, E);

    // 3. message passing: B1(input) -> B2 -> B3 -> B2 (gather-fused GEMM)
    const float* cur = B1;
    float* nxt[3] = { B2, B3, B2 };
    for (int it = 0; it < 3; ++it) {
        agg_kernel<<<N / 2, 256, 0, stream>>>(cur, a2b, msg_atom, N);
        gemm_mp<<<gE, 256, 0, stream>>>(
            msg_atom, cur, b2a, b2revb, B1, wh[it], nxt[it], E);
        cur = nxt[it];
    }
    // final message_bond = B2; B1, B3 now dead

    // 4. outsum = msg_atom @ skip_w.T + skip_b   (attention adds on top)
    gemm128<false, false, true><<<gN, 256, 0, stream>>>(
        msg_atom, skip_w, nullptr, skip_b, outsum, N, 128);

    // 5. TransformerConv, one head at a time
    for (int h = 0; h < 8; ++h) {
        const size_t w_off = (size_t)h * 128 * 128;
        gemm128<false, false, true><<<gN, 256, 0, stream>>>(
            msg_atom, q_w + w_off, nullptr, q_b + h * 128, q_h, N, 128);
        gemm128<false, false, true><<<gN, 256, 0, stream>>>(
            msg_atom, k_w + w_off, nullptr, k_b + h * 128, k_h, N, 128);
        gemm128<false, false, false><<<gE, 256, 0, stream>>>(
            B2, e_w + w_off, nullptr, nullptr, e_h, E, 128);
        attn_pass1<<<(N + 3) / 4, 256, 0, stream>>>(
            q_h, k_h, e_h, srcA, offsets, elist, alpha, N);
        gemm128<false, false, true><<<gN, 256, 0, stream>>>(
            msg_atom, v_w + w_off, nullptr, v_b + h * 128, v_h, N, 128);
        attn_pass2<<<(N + 3) / 4, 256, 0, stream>>>(
            v_h, e_h, srcA, offsets, elist, alpha, outsum, N);
    }

    // 6. Set2Set + output projection (outsum == atom_hiddens)
    qv_kernel<<<1, 128, 0, stream>>>(lstm_bih, lstm_bhh, qvb);
    const int M = N / 20;  // 3000 molecules
    s2s_kernel<<<(M + 3) / 4, 256, 0, stream>>>(outsum, qvb, wo_w, wo_b, (float*)d_out, M);
}

// Round 6
// 2331.730 us; speedup vs baseline: 1.7755x; 1.0873x over previous
//
#include <hip/hip_runtime.h>
#include <hip/hip_bf16.h>

// ---------------- utility kernels ------------------------------------------
__global__ void zero_u32(unsigned int* __restrict__ p, long long n)
{
    long long i = (long long)blockIdx.x * 256 + threadIdx.x;
    if (i < n) p[i] = 0u;
}

__global__ void sentinel_f32(float* __restrict__ p, long long n, float v)
{
    long long i = (long long)blockIdx.x * 256 + threadIdx.x;
    if (i < n) p[i] = v;
}

// ---------------- multi-segment GEMM ----------------------------------------
// C[M,128] = act(A[M,K] @ W[128,K]^T + bias?), up to 4 independent segments
// packed into one grid for machine fill. 128x128 tile, BK=16, 8x8/thread.
struct GSeg {
    const float* A; const float* W; const float* bias; float* C;
    int M; int K; int bend;   // bend = exclusive block-id end of this segment
};
struct GParams { GSeg s[4]; };

template<bool RELU>
__global__ __launch_bounds__(256) void gemm_multi(GParams P, int nseg)
{
    __shared__ float As[16][132];
    __shared__ float Ws[16][132];
    const int b = blockIdx.x;
    int si = 0, bbeg = 0;
    while (si + 1 < nseg && b >= P.s[si].bend) { bbeg = P.s[si].bend; ++si; }
    const GSeg S = P.s[si];
    const int tid = threadIdx.x;
    const int tx = tid & 15, ty = tid >> 4;
    const int row0 = (b - bbeg) * 128;
    const int r  = tid >> 2;          // 0..63
    const int k4 = (tid & 3) * 4;     // 0,4,8,12
    float acc[8][8] = {};
    for (int k0 = 0; k0 < S.K; k0 += 16) {
        const bool fullk = (k0 + 16 <= S.K);
#pragma unroll
        for (int c = 0; c < 2; ++c) {
            int rr = r + c * 64;
            int gm = row0 + rr;
            float4 av = make_float4(0.f, 0.f, 0.f, 0.f);
            if (gm < S.M) {
                const float* p = S.A + (size_t)gm * S.K + k0 + k4;
                if (fullk) av = *(const float4*)p;
                else {
                    if (k0 + k4     < S.K) av.x = p[0];
                    if (k0 + k4 + 1 < S.K) av.y = p[1];
                    if (k0 + k4 + 2 < S.K) av.z = p[2];
                    if (k0 + k4 + 3 < S.K) av.w = p[3];
                }
            }
            As[k4 + 0][rr] = av.x; As[k4 + 1][rr] = av.y;
            As[k4 + 2][rr] = av.z; As[k4 + 3][rr] = av.w;
            float4 wv = make_float4(0.f, 0.f, 0.f, 0.f);
            const float* pw = S.W + (size_t)rr * S.K + k0 + k4;
            if (fullk) wv = *(const float4*)pw;
            else {
                if (k0 + k4     < S.K) wv.x = pw[0];
                if (k0 + k4 + 1 < S.K) wv.y = pw[1];
                if (k0 + k4 + 2 < S.K) wv.z = pw[2];
                if (k0 + k4 + 3 < S.K) wv.w = pw[3];
            }
            Ws[k4 + 0][rr] = wv.x; Ws[k4 + 1][rr] = wv.y;
            Ws[k4 + 2][rr] = wv.z; Ws[k4 + 3][rr] = wv.w;
        }
        __syncthreads();
#pragma unroll
        for (int kk = 0; kk < 16; ++kk) {
            float4 a0 = *(const float4*)&As[kk][ty * 4];
            float4 a1 = *(const float4*)&As[kk][64 + ty * 4];
            float4 w0 = *(const float4*)&Ws[kk][tx * 4];
            float4 w1 = *(const float4*)&Ws[kk][64 + tx * 4];
            float a[8] = {a0.x, a0.y, a0.z, a0.w, a1.x, a1.y, a1.z, a1.w};
            float w[8] = {w0.x, w0.y, w0.z, w0.w, w1.x, w1.y, w1.z, w1.w};
#pragma unroll
            for (int i = 0; i < 8; ++i)
#pragma unroll
                for (int j = 0; j < 8; ++j)
                    acc[i][j] += a[i] * w[j];
        }
        __syncthreads();
    }
    float bs[8];
    if (S.bias) {
#pragma unroll
        for (int j = 0; j < 4; ++j) {
            bs[j]     = S.bias[tx * 4 + j];
            bs[j + 4] = S.bias[64 + tx * 4 + j];
        }
    } else {
#pragma unroll
        for (int j = 0; j < 8; ++j) bs[j] = 0.f;
    }
#pragma unroll
    for (int i = 0; i < 8; ++i) {
        int rr = (i < 4) ? (ty * 4 + i) : (64 + ty * 4 + i - 4);
        int gm = row0 + rr;
        if (gm >= S.M) continue;
#pragma unroll
        for (int jh = 0; jh < 2; ++jh) {
            float4 v;
            v.x = acc[i][jh * 4 + 0] + bs[jh * 4 + 0];
            v.y = acc[i][jh * 4 + 1] + bs[jh * 4 + 1];
            v.z = acc[i][jh * 4 + 2] + bs[jh * 4 + 2];
            v.w = acc[i][jh * 4 + 3] + bs[jh * 4 + 3];
            if (RELU) {
                v.x = fmaxf(v.x, 0.f); v.y = fmaxf(v.y, 0.f);
                v.z = fmaxf(v.z, 0.f); v.w = fmaxf(v.w, 0.f);
            }
            *(float4*)&S.C[(size_t)gm * 128 + jh * 64 + tx * 4] = v;
        }
    }
}

// ---------------- BM=64 GEMM (for small grids): C[M,128] = A@W^T + bias -----
__global__ __launch_bounds__(256) void gemm64(
    const float* __restrict__ A, const float* __restrict__ W,
    const float* __restrict__ bias, float* __restrict__ C, int M)
{
    __shared__ float As[16][68];
    __shared__ float Ws[16][132];
    const int tid = threadIdx.x;
    const int tx = tid & 15, ty = tid >> 4;
    const int row0 = blockIdx.x * 64;
    const int r  = tid >> 2;
    const int k4 = (tid & 3) * 4;
    float acc[4][8] = {};
    for (int k0 = 0; k0 < 128; k0 += 16) {
        {
            int gm = row0 + r;
            float4 av = make_float4(0.f, 0.f, 0.f, 0.f);
            if (gm < M) av = *(const float4*)(A + (size_t)gm * 128 + k0 + k4);
            As[k4 + 0][r] = av.x; As[k4 + 1][r] = av.y;
            As[k4 + 2][r] = av.z; As[k4 + 3][r] = av.w;
        }
#pragma unroll
        for (int c = 0; c < 2; ++c) {
            int rr = r + c * 64;
            float4 wv = *(const float4*)(W + (size_t)rr * 128 + k0 + k4);
            Ws[k4 + 0][rr] = wv.x; Ws[k4 + 1][rr] = wv.y;
            Ws[k4 + 2][rr] = wv.z; Ws[k4 + 3][rr] = wv.w;
        }
        __syncthreads();
#pragma unroll
        for (int kk = 0; kk < 16; ++kk) {
            float4 a0 = *(const float4*)&As[kk][ty * 4];
            float4 w0 = *(const float4*)&Ws[kk][tx * 4];
            float4 w1 = *(const float4*)&Ws[kk][64 + tx * 4];
            float a[4] = {a0.x, a0.y, a0.z, a0.w};
            float w[8] = {w0.x, w0.y, w0.z, w0.w, w1.x, w1.y, w1.z, w1.w};
#pragma unroll
            for (int i = 0; i < 4; ++i)
#pragma unroll
                for (int j = 0; j < 8; ++j)
                    acc[i][j] += a[i] * w[j];
        }
        __syncthreads();
    }
    float bs[8];
#pragma unroll
    for (int j = 0; j < 4; ++j) {
        bs[j]     = bias ? bias[tx * 4 + j] : 0.f;
        bs[j + 4] = bias ? bias[64 + tx * 4 + j] : 0.f;
    }
#pragma unroll
    for (int i = 0; i < 4; ++i) {
        int gm = row0 + ty * 4 + i;
        if (gm >= M) continue;
#pragma unroll
        for (int jh = 0; jh < 2; ++jh) {
            float4 v;
            v.x = acc[i][jh * 4 + 0] + bs[jh * 4 + 0];
            v.y = acc[i][jh * 4 + 1] + bs[jh * 4 + 1];
            v.z = acc[i][jh * 4 + 2] + bs[jh * 4 + 2];
            v.w = acc[i][jh * 4 + 3] + bs[jh * 4 + 3];
            *(float4*)&C[(size_t)gm * 128 + jh * 64 + tx * 4] = v;
        }
    }
}

// ---- MP GEMM, BM=64, gathered A: C[e] = relu(inb[e] + (ma[b2a]-bond[b2revb])@wh^T)
__global__ __launch_bounds__(256) void gemm_mp(
    const float* __restrict__ ma, const float* __restrict__ bond,
    const int* __restrict__ b2a, const int* __restrict__ b2revb,
    const float* __restrict__ inb, const float* __restrict__ wh,
    float* __restrict__ C)
{
    __shared__ float As[16][68];
    __shared__ float Ws[16][132];
    __shared__ int ia[64], ir[64];
    const int tid = threadIdx.x;
    const int tx = tid & 15, ty = tid >> 4;
    const int row0 = blockIdx.x * 64;
    const int r  = tid >> 2;
    const int k4 = (tid & 3) * 4;
    if (tid < 64)       ia[tid]      = b2a[row0 + tid];
    else if (tid < 128) ir[tid - 64] = b2revb[row0 + tid - 64];
    __syncthreads();
    float acc[4][8] = {};
    for (int k0 = 0; k0 < 128; k0 += 16) {
        {
            float4 x = *(const float4*)(ma   + (size_t)ia[r] * 128 + k0 + k4);
            float4 y = *(const float4*)(bond + (size_t)ir[r] * 128 + k0 + k4);
            As[k4 + 0][r] = x.x - y.x; As[k4 + 1][r] = x.y - y.y;
            As[k4 + 2][r] = x.z - y.z; As[k4 + 3][r] = x.w - y.w;
        }
#pragma unroll
        for (int c = 0; c < 2; ++c) {
            int rr = r + c * 64;
            float4 wv = *(const float4*)(wh + (size_t)rr * 128 + k0 + k4);
            Ws[k4 + 0][rr] = wv.x; Ws[k4 + 1][rr] = wv.y;
            Ws[k4 + 2][rr] = wv.z; Ws[k4 + 3][rr] = wv.w;
        }
        __syncthreads();
#pragma unroll
        for (int kk = 0; kk < 16; ++kk) {
            float4 a0 = *(const float4*)&As[kk][ty * 4];
            float4 w0 = *(const float4*)&Ws[kk][tx * 4];
            float4 w1 = *(const float4*)&Ws[kk][64 + tx * 4];
            float a[4] = {a0.x, a0.y, a0.z, a0.w};
            float w[8] = {w0.x, w0.y, w0.z, w0.w, w1.x, w1.y, w1.z, w1.w};
#pragma unroll
            for (int i = 0; i < 4; ++i)
#pragma unroll
                for (int j = 0; j < 8; ++j)
                    acc[i][j] += a[i] * w[j];
        }
        __syncthreads();
    }
#pragma unroll
    for (int i = 0; i < 4; ++i) {
        int gm = row0 + ty * 4 + i;
#pragma unroll
        for (int jh = 0; jh < 2; ++jh) {
            int cc = jh * 64 + tx * 4;
            float4 o = *(const float4*)&inb[(size_t)gm * 128 + cc];
            float4 v;
            v.x = fmaxf(acc[i][jh * 4 + 0] + o.x, 0.f);
            v.y = fmaxf(acc[i][jh * 4 + 1] + o.y, 0.f);
            v.z = fmaxf(acc[i][jh * 4 + 2] + o.z, 0.f);
            v.w = fmaxf(acc[i][jh * 4 + 3] + o.w, 0.f);
            *(float4*)&C[(size_t)gm * 128 + cc] = v;
        }
    }
}

// ---------------- aggregation (float4, 8 nodes/block) ------------------------
__global__ __launch_bounds__(256) void agg_kernel(
    const float* __restrict__ bond, const int* __restrict__ a2b,
    float* __restrict__ ma, int N)
{
    int n = blockIdx.x * 8 + (threadIdx.x >> 5);
    if (n >= N) return;
    int d4 = (threadIdx.x & 31) * 4;
    const int* ix = a2b + (size_t)n * 6;
    float4 s = make_float4(0.f, 0.f, 0.f, 0.f);
    float4 mx = make_float4(-3.0e38f, -3.0e38f, -3.0e38f, -3.0e38f);
#pragma unroll
    for (int j = 0; j < 6; ++j) {
        float4 v = *(const float4*)(bond + (size_t)ix[j] * 128 + d4);
        s.x += v.x; s.y += v.y; s.z += v.z; s.w += v.w;
        mx.x = fmaxf(mx.x, v.x); mx.y = fmaxf(mx.y, v.y);
        mx.z = fmaxf(mx.z, v.z); mx.w = fmaxf(mx.w, v.w);
    }
    float* mp = ma + (size_t)n * 128 + d4;
    float4 o = *(const float4*)mp;
    o.x += s.x * mx.x; o.y += s.y * mx.y; o.z += s.z * mx.z; o.w += s.w * mx.w;
    *(float4*)mp = o;
}

// ---------------- CSR build over dst ----------------------------------------
__global__ void count_kernel(const int* __restrict__ dst, int* __restrict__ counts, int E)
{
    int e = blockIdx.x * 256 + threadIdx.x;
    if (e < E) atomicAdd(&counts[dst[e]], 1);
}

__global__ __launch_bounds__(1024) void scan_kernel(
    const int* __restrict__ counts, int* __restrict__ offsets, int N)
{
    __shared__ int sums[1024];
    int t = threadIdx.x;
    int chunk = (N + 1023) >> 10;
    int b = t * chunk;
    int e = b + chunk; if (e > N) e = N;
    int s = 0;
    for (int i = b; i < e; ++i) s += counts[i];
    sums[t] = s;
    __syncthreads();
    for (int off = 1; off < 1024; off <<= 1) {
        int v = (t >= off) ? sums[t - off] : 0;
        __syncthreads();
        sums[t] += v;
        __syncthreads();
    }
    int run = sums[t] - s;
    for (int i = b; i < e; ++i) { offsets[i] = run; run += counts[i]; }
    if (t == 1023) offsets[N] = sums[1023];
}

__global__ void fill_kernel(const int* __restrict__ dst, const int* __restrict__ offsets,
                            int* __restrict__ cursor, int* __restrict__ elist, int E)
{
    int e = blockIdx.x * 256 + threadIdx.x;
    if (e < E) {
        int d = dst[e];
        int pos = offsets[d] + atomicAdd(&cursor[d], 1);
        elist[pos] = e;
    }
}

// ---------------- attention pass 1: logits -> normalized alpha --------------
__global__ __launch_bounds__(256) void attn_pass1(
    const float* __restrict__ qh, const float* __restrict__ kh,
    const float* __restrict__ eh, const int* __restrict__ srcA,
    const int* __restrict__ offs, const int* __restrict__ elist,
    float* __restrict__ alpha, int N)
{
    int n = blockIdx.x * 4 + (threadIdx.x >> 6);
    if (n >= N) return;
    int l = threadIdx.x & 63;
    const float rs = 0.08838834764831845f;  // 1/sqrt(128)
    float2 q2 = ((const float2*)(qh + (size_t)n * 128))[l];
    int b = offs[n], en = offs[n + 1];
    float m = -3.0e38f, denom = 0.f;
    int ie = b;
    for (; ie + 2 <= en; ie += 2) {
        int e0 = elist[ie], e1 = elist[ie + 1];
        int s0 = srcA[e0], s1 = srcA[e1];
        float2 k0v = ((const float2*)(kh + (size_t)s0 * 128))[l];
        float2 e0v = ((const float2*)(eh + (size_t)e0 * 128))[l];
        float2 k1v = ((const float2*)(kh + (size_t)s1 * 128))[l];
        float2 e1v = ((const float2*)(eh + (size_t)e1 * 128))[l];
        float p0 = q2.x * (k0v.x + e0v.x) + q2.y * (k0v.y + e0v.y);
        float p1 = q2.x * (k1v.x + e1v.x) + q2.y * (k1v.y + e1v.y);
        p0 += __shfl_xor(p0, 1);  p1 += __shfl_xor(p1, 1);
        p0 += __shfl_xor(p0, 2);  p1 += __shfl_xor(p1, 2);
        p0 += __shfl_xor(p0, 4);  p1 += __shfl_xor(p1, 4);
        p0 += __shfl_xor(p0, 8);  p1 += __shfl_xor(p1, 8);
        p0 += __shfl_xor(p0, 16); p1 += __shfl_xor(p1, 16);
        p0 += __shfl_xor(p0, 32); p1 += __shfl_xor(p1, 32);
        float l0 = p0 * rs, l1 = p1 * rs;
        if (l == 0) { alpha[ie] = l0; alpha[ie + 1] = l1; }
        float mn = fmaxf(m, fmaxf(l0, l1));
        float sc = __expf(m - mn);
        denom = denom * sc + __expf(l0 - mn) + __expf(l1 - mn);
        m = mn;
    }
    if (ie < en) {
        int e0 = elist[ie];
        int s0 = srcA[e0];
        float2 k0v = ((const float2*)(kh + (size_t)s0 * 128))[l];
        float2 e0v = ((const float2*)(eh + (size_t)e0 * 128))[l];
        float p0 = q2.x * (k0v.x + e0v.x) + q2.y * (k0v.y + e0v.y);
        p0 += __shfl_xor(p0, 1);  p0 += __shfl_xor(p0, 2);
        p0 += __shfl_xor(p0, 4);  p0 += __shfl_xor(p0, 8);
        p0 += __shfl_xor(p0, 16); p0 += __shfl_xor(p0, 32);
        float l0 = p0 * rs;
        if (l == 0) alpha[ie] = l0;
        float mn = fmaxf(m, l0);
        denom = denom * __expf(m - mn) + __expf(l0 - mn);
        m = mn;
    }
    if (l == 0 && b < en) {
        float invd = 1.f / (denom + 1e-16f);
        for (int i = b; i < en; ++i)
            alpha[i] = __expf(alpha[i] - m) * invd;
    }
}

// ---------------- attention pass 2: outsum += 0.125 * alpha*(v[src]+eattr) --
__global__ __launch_bounds__(256) void attn_pass2(
    const float* __restrict__ vh, const float* __restrict__ eh,
    const int* __restrict__ srcA, const int* __restrict__ offs,
    const int* __restrict__ elist, const float* __restrict__ alpha,
    float* __restrict__ outsum, int N)
{
    int n = blockIdx.x * 4 + (threadIdx.x >> 6);
    if (n >= N) return;
    int l = threadIdx.x & 63;
    int b = offs[n], en = offs[n + 1];
    float a0 = 0.f, a1 = 0.f;
    int ie = b;
    for (; ie + 2 <= en; ie += 2) {
        int e0 = elist[ie], e1 = elist[ie + 1];
        int s0 = srcA[e0], s1 = srcA[e1];
        float al0 = alpha[ie], al1 = alpha[ie + 1];
        float2 v0 = ((const float2*)(vh + (size_t)s0 * 128))[l];
        float2 e0v = ((const float2*)(eh + (size_t)e0 * 128))[l];
        float2 v1 = ((const float2*)(vh + (size_t)s1 * 128))[l];
        float2 e1v = ((const float2*)(eh + (size_t)e1 * 128))[l];
        a0 += al0 * (v0.x + e0v.x) + al1 * (v1.x + e1v.x);
        a1 += al0 * (v0.y + e0v.y) + al1 * (v1.y + e1v.y);
    }
    if (ie < en) {
        int e0 = elist[ie];
        int s0 = srcA[e0];
        float al0 = alpha[ie];
        float2 v0 = ((const float2*)(vh + (size_t)s0 * 128))[l];
        float2 e0v = ((const float2*)(eh + (size_t)e0 * 128))[l];
        a0 += al0 * (v0.x + e0v.x);
        a1 += al0 * (v0.y + e0v.y);
    }
    float* op = outsum + (size_t)n * 128 + 2 * l;
    op[0] += 0.125f * a0;
    op[1] += 0.125f * a1;
}

// ---------------- Set2Set ----------------------------------------------------
__global__ void qv_kernel(const float* __restrict__ bih, const float* __restrict__ bhh,
                          float* __restrict__ qv)
{
    int t = threadIdx.x;  // 128 threads
    float gi = bih[t] + bhh[t];
    float gg = bih[256 + t] + bhh[256 + t];
    float go = bih[384 + t] + bhh[384 + t];
    float sig_i = 1.f / (1.f + __expf(-gi));
    float c = sig_i * tanhf(gg);
    float sig_o = 1.f / (1.f + __expf(-go));
    qv[t] = sig_o * tanhf(c);
}

__global__ __launch_bounds__(256) void s2s_kernel(
    const float* __restrict__ ah, const float* __restrict__ qv,
    const float* __restrict__ wo_w, const float* __restrict__ wo_b,
    float* __restrict__ out, int M)
{
    __shared__ float rsh[4][128];
    __shared__ float qsh[128];
    int wv = threadIdx.x >> 6, l = threadIdx.x & 63;
    if (threadIdx.x < 128) qsh[threadIdx.x] = qv[threadIdx.x];
    __syncthreads();
    int m = blockIdx.x * 4 + wv;
    bool active = (m < M);
    if (active) {
        const float* x = ah + (size_t)m * 20 * 128;
        float q0 = qsh[2 * l], q1 = qsh[2 * l + 1];
        float e[20]; float mx = -3.0e38f;
#pragma unroll
        for (int a = 0; a < 20; ++a) {
            float part = x[a * 128 + 2 * l] * q0 + x[a * 128 + 2 * l + 1] * q1;
            part += __shfl_xor(part, 1);  part += __shfl_xor(part, 2);
            part += __shfl_xor(part, 4);  part += __shfl_xor(part, 8);
            part += __shfl_xor(part, 16); part += __shfl_xor(part, 32);
            e[a] = part; mx = fmaxf(mx, part);
        }
        float sum = 0.f;
#pragma unroll
        for (int a = 0; a < 20; ++a) { e[a] = __expf(e[a] - mx); sum += e[a]; }
        float invs = 1.f / (sum + 1e-16f);
        float r0 = 0.f, r1 = 0.f;
#pragma unroll
        for (int a = 0; a < 20; ++a) {
            float w = e[a] * invs;
            r0 += w * x[a * 128 + 2 * l];
            r1 += w * x[a * 128 + 2 * l + 1];
        }
        rsh[wv][2 * l] = r0; rsh[wv][2 * l + 1] = r1;
    }
    __syncthreads();
    if (active) {
#pragma unroll
        for (int dd = 0; dd < 2; ++dd) {
            int d = 2 * l + dd;
            float acc = wo_b[d];
            const float* wr = wo_w + (size_t)d * 256;
            for (int j = 0; j < 128; ++j)
                acc += wr[j] * qsh[j] + wr[128 + j] * rsh[wv][j];
            out[(size_t)m * 128 + d] = acc;
        }
    }
}

// ---------------- launch -----------------------------------------------------
extern "C" void kernel_launch(void* const* d_in, const int* in_sizes, int n_in,
                              void* d_out, int out_size, void* d_ws, size_t ws_size,
                              hipStream_t stream)
{
    const int N = 60000, E = 120000, FA = 133, FB = 147;
    const float* f_atoms  = (const float*)d_in[0];
    const float* f_bonds  = (const float*)d_in[1];
    const float* wi_atom  = (const float*)d_in[2];
    const float* wi_bond  = (const float*)d_in[3];
    const float* wh[3]    = { (const float*)d_in[4], (const float*)d_in[5], (const float*)d_in[6] };
    const float* q_w      = (const float*)d_in[7];
    const float* q_b      = (const float*)d_in[8];
    const float* k_w      = (const float*)d_in[9];
    const float* k_b      = (const float*)d_in[10];
    const float* v_w      = (const float*)d_in[11];
    const float* v_b      = (const float*)d_in[12];
    const float* e_w      = (const float*)d_in[13];
    const float* skip_w   = (const float*)d_in[14];
    const float* skip_b   = (const float*)d_in[15];
    const float* lstm_bih = (const float*)d_in[18];
    const float* lstm_bhh = (const float*)d_in[19];
    const float* wo_w     = (const float*)d_in[20];
    const float* wo_b     = (const float*)d_in[21];
    const int* a2b    = (const int*)d_in[22];
    const int* b2a    = (const int*)d_in[23];
    const int* b2revb = (const int*)d_in[24];
    const int* bonds  = (const int*)d_in[25];
    const int* srcA = bonds;
    const int* dstA = bonds + E;

    // ---- workspace plan (~248 MB, proven to fit) ----
    const size_t NB = (size_t)N * 128;
    const size_t EB = (size_t)E * 128;
    char* ws = (char*)d_ws;
    size_t off = 0;
    auto alloc = [&](size_t bytes) -> char* {
        char* p = ws + off; off += (bytes + 255) & ~255ULL; return p;
    };
    float* msg_atom = (float*)alloc(NB * 4);   // atoms, whole run
    float* B1       = (float*)alloc(EB * 4);   // input_bond -> [q|k] -> [v|k]
    float* B2       = (float*)alloc(EB * 4);   // bond ping (final msg_bond)
    float* B3       = (float*)alloc(EB * 4);   // bond pong -> eattr_h
    float* outsum   = (float*)alloc(NB * 4);   // skip-init, attn accum, = ah
    float* alpha    = (float*)alloc((size_t)E * 4);
    int* counts  = (int*)alloc((size_t)N * 2 * 4);   // counts | cursor contiguous
    int* cursor  = counts + N;
    int* offsets = (int*)alloc((size_t)(N + 1) * 4);
    int* elist   = (int*)alloc((size_t)E * 4);
    float* qvb   = (float*)alloc(128 * 4);

    if (off > ws_size) {
        long long n = out_size;
        sentinel_f32<<<(int)((n + 255) / 256), 256, 0, stream>>>((float*)d_out, n, 1.0e9f);
        return;
    }

    float* q_h = B1;            // [N,128]
    float* k_h = B1 + NB;       // [N,128]
    float* v_h = B1;            // [N,128] overwrites q after pass1
    float* e_h = B3;            // [E,128]

    const int gN128 = (N + 127) / 128;   // 469
    const int gE128 = (E + 127) / 128;   // 938
    const int gN64  = (N + 63) / 64;     // 938
    const int gE64  = E / 64;            // 1875 exact

    // 0. zero CSR state (graph-capture/replay-safe)
    zero_u32<<<(2 * N + 255) / 256, 256, 0, stream>>>((unsigned int*)counts, 2 * N);

    // 1. input projections (one merged launch, per-segment K)
    {
        GParams P{};
        P.s[0] = { f_atoms, wi_atom, nullptr, msg_atom, N, FA, gN128 };
        P.s[1] = { f_bonds, wi_bond, nullptr, B1,       E, FB, gN128 + gE128 };
        gemm_multi<true><<<gN128 + gE128, 256, 0, stream>>>(P, 2);
    }

    // 2. CSR over dst
    count_kernel<<<(E + 255) / 256, 256, 0, stream>>>(dstA, counts, E);
    scan_kernel<<<1, 1024, 0, stream>>>(counts, offsets, N);
    fill_kernel<<<(E + 255) / 256, 256, 0, stream>>>(dstA, offsets, cursor, elist, E);

    // 3. message passing: B1(input) -> B2 -> B3 -> B2 (gather-fused GEMM)
    const float* cur = B1;
    float* nxt[3] = { B2, B3, B2 };
    for (int it = 0; it < 3; ++it) {
        agg_kernel<<<(N + 7) / 8, 256, 0, stream>>>(cur, a2b, msg_atom, N);
        gemm_mp<<<gE64, 256, 0, stream>>>(
            msg_atom, cur, b2a, b2revb, B1, wh[it], nxt[it]);
        cur = nxt[it];
    }
    // final message_bond = B2; B1, B3 now dead

    // 4./5. TransformerConv per head; skip-GEMM rides in head 0's launch
    for (int h = 0; h < 8; ++h) {
        const size_t w_off = (size_t)h * 128 * 128;
        GParams P{};
        P.s[0] = { B2,       e_w + w_off, nullptr,        e_h, E, 128, gE128 };
        P.s[1] = { msg_atom, q_w + w_off, q_b + h * 128,  q_h, N, 128, gE128 + gN128 };
        P.s[2] = { msg_atom, k_w + w_off, k_b + h * 128,  k_h, N, 128, gE128 + 2 * gN128 };
        int nseg = 3, nblk = gE128 + 2 * gN128;
        if (h == 0) {
            P.s[3] = { msg_atom, skip_w, skip_b, outsum, N, 128, gE128 + 3 * gN128 };
            nseg = 4; nblk += gN128;
        }
        gemm_multi<false><<<nblk, 256, 0, stream>>>(P, nseg);
        attn_pass1<<<(N + 3) / 4, 256, 0, stream>>>(
            q_h, k_h, e_h, srcA, offsets, elist, alpha, N);
        gemm64<<<gN64, 256, 0, stream>>>(msg_atom, v_w + w_off, v_b + h * 128, v_h, N);
        attn_pass2<<<(N + 3) / 4, 256, 0, stream>>>(
            v_h, e_h, srcA, offsets, elist, alpha, outsum, N);
    }

    // 6. Set2Set + output projection (outsum == atom_hiddens)
    qv_kernel<<<1, 128, 0, stream>>>(lstm_bih, lstm_bhh, qvb);
    const int M = N / 20;  // 3000 molecules
    s2s_kernel<<<(M + 3) / 4, 256, 0, stream>>>(outsum, qvb, wo_w, wo_b, (float*)d_out, M);
}